// Round 1
// baseline (1006.592 us; speedup 1.0000x reference)
//
#include <hip/hip_runtime.h>
#include <math.h>

// DelayAndSum: out[b,t] = (1/S) * sum_s x[b, t+d_s, s] * (t+d_s < T)
// B=16, T=100000, S=128, d_s = rint(s*sin(ANGLE)/2) in [0,32].
//
// R3: 33-slot delay-group formulation.
// Host verifies (from the exact libm delays) that d_s == (s+1)>>2, i.e.
// sensors {4L-1, 4L, 4L+1, 4L+2} all share delay L (L = 0..31) and sensor
// 127 alone has delay 32. Then lane L loads a float4 shifted one float left
// (dword-aligned vector loads are supported by CDNA) and its plain 4-sum IS
// the group-L row sum:
//    R_L[u] = x[u,4L-1] + x[u,4L] + x[u,4L+1] + x[u,4L+2]   (lane 0: 3-sum)
//    R_32[u] = x[u,127]                                      (lane 31 extra)
// Slot j stores row u at P[j*FRSTR + (u-t0) - j] (delay-rebased), so
// phase 2 is 33 ds_read_b32 at ONE vgpr address + immediate offsets:
//    out[t0+tid] = (1/S) * sum_j P[j*FRSTR + tid]
// LDS = 33*226*4 = 29832 B -> 5 blocks/CU (20 waves, vs 2 blocks/8 waves in
// R2). Write bank index = 225*L + r, 225 % 32 == 1 -> conflict-free.
// If the delay pattern ever differs, falls back to the verified R2 kernel.

#define SENS 128

// ---------------- fast path: 33 delay-group slots ----------------
#define FTT   224
#define FROWS (FTT + 32)        // 256 rows staged per tile
#define FRSTR (FTT + 2)         // 226 (even): write idx 225*L+r -> 32 banks
#define FNSLOT 33

__global__ __launch_bounds__(256, 5)
void das3_kernel(const float* __restrict__ x, float* __restrict__ out, int T) {
    __shared__ float P[FNSLOT * FRSTR];   // 29832 B -> 5 blocks/CU

    const int tid = threadIdx.x;
    const int b   = blockIdx.y;
    const int t0  = blockIdx.x * FTT;
    const int L   = tid & 31;             // delay-group / chunk id
    const int rb  = tid >> 5;             // row-within-sweep (0..7)

    // lane L reads sensors [4L-1 .. 4L+2]; lane 0 reads [0..3], drops .w
    const int s0 = 4 * L - (L > 0);
    const float* __restrict__ xrow  = x + (size_t)b * (size_t)T * SENS + s0;
    const float* __restrict__ xlast = x + (size_t)b * (size_t)T * SENS + (SENS - 1);

    float* __restrict__ Pw  = P + L * FRSTR - L;     // slot L, rebased by -L
    float* __restrict__ PwE = P + 32 * FRSTR - 32;   // slot 32 (lane 31 only)

    if (t0 + FROWS <= T) {
        // hot path: 4 batches x 8 float4 loads kept in flight, then stores
        #pragma unroll
        for (int bb = 0; bb < 4; ++bb) {
            float4 v[8];
            float  vl[8];
            #pragma unroll
            for (int k = 0; k < 8; ++k) {
                const int r = (bb * 8 + k) * 8 + rb;
                v[k] = *(const float4*)(xrow + (size_t)(t0 + r) * SENS);
            }
            if (L == 31) {
                #pragma unroll
                for (int k = 0; k < 8; ++k) {
                    const int r = (bb * 8 + k) * 8 + rb;
                    vl[k] = xlast[(size_t)(t0 + r) * SENS];
                }
            }
            #pragma unroll
            for (int k = 0; k < 8; ++k) {
                const int r = (bb * 8 + k) * 8 + rb;
                const float4 q = v[k];
                const float R = q.x + q.y + q.z + (L ? q.w : 0.0f);
                if (r >= L && r < L + FTT) Pw[r] = R;      // bank-conflict-free
                if (L == 31 && r >= 32)    PwE[r] = vl[k]; // slot 32 (r<256 always)
            }
        }
    } else {
        // tail tile: rows past T stay zero (this IS the validity mask)
        for (int i = tid; i < FNSLOT * FRSTR; i += 256) P[i] = 0.0f;
        __syncthreads();
        for (int sw = 0; sw < FROWS / 8; ++sw) {
            const int r = sw * 8 + rb;
            const int u = t0 + r;
            if (u < T) {
                const float4 q = *(const float4*)(xrow + (size_t)u * SENS);
                const float R = q.x + q.y + q.z + (L ? q.w : 0.0f);
                if (r >= L && r < L + FTT) Pw[r] = R;
                if (L == 31 && r >= 32)    PwE[r] = xlast[(size_t)u * SENS];
            }
        }
    }
    __syncthreads();

    // phase 2: 33 conflict-free LDS reads, immediate offsets off one address
    const int t = t0 + tid;
    if (tid < FTT && t < T) {
        float acc = 0.0f;
        #pragma unroll
        for (int j = 0; j < FNSLOT; ++j)
            acc += P[j * FRSTR + tid];
        out[(size_t)b * T + t] = acc * (1.0f / SENS);
    }
}

// ---------------- fallback: verified R2 kernel (64 partial slots) ----------------
#define TT   256
#define ROWS (TT + 32)
#define RSTR (ROWS + 1)
#define NSLOT 64

struct Tabs {
    int off[NSLOT];
    unsigned cm1, cm2, cm3;
};

__global__ __launch_bounds__(256)
void das2_kernel(const float* __restrict__ x, float* __restrict__ out,
                 Tabs tb, int T) {
    __shared__ float P[NSLOT * RSTR];

    const int tid = threadIdx.x;
    const int b   = blockIdx.y;
    const int t0  = blockIdx.x * TT;

    const int L = tid & 31;
    const bool c1 = (tb.cm1 >> L) & 1u;
    const bool c2 = (tb.cm2 >> L) & 1u;
    const bool c3 = (tb.cm3 >> L) & 1u;
    const int rb = tid >> 5;
    float* __restrict__ Pw = P + (2 * L) * RSTR;
    const float* __restrict__ xb = x + (size_t)b * (size_t)T * SENS + 4 * L;

    if (t0 + ROWS <= T) {
        #pragma unroll 4
        for (int sw = 0; sw < ROWS / 8; ++sw) {
            const int r = sw * 8 + rb;
            const float4 v = *(const float4*)(xb + (size_t)(t0 + r) * SENS);
            float a = v.x;
            a += c1 ? v.y : 0.0f;
            a += c2 ? v.z : 0.0f;
            a += c3 ? v.w : 0.0f;
            const float g = (c1 ? 0.0f : v.y) + (c2 ? 0.0f : v.z)
                          + (c3 ? 0.0f : v.w);
            Pw[r]        = a;
            Pw[RSTR + r] = g;
        }
    } else {
        for (int i = tid; i < NSLOT * RSTR; i += 256) P[i] = 0.0f;
        __syncthreads();
        for (int sw = 0; sw < ROWS / 8; ++sw) {
            const int r = sw * 8 + rb;
            const int u = t0 + r;
            if (u < T) {
                const float4 v = *(const float4*)(xb + (size_t)u * SENS);
                float a = v.x;
                a += c1 ? v.y : 0.0f;
                a += c2 ? v.z : 0.0f;
                a += c3 ? v.w : 0.0f;
                const float g = (c1 ? 0.0f : v.y) + (c2 ? 0.0f : v.z)
                              + (c3 ? 0.0f : v.w);
                Pw[r]        = a;
                Pw[RSTR + r] = g;
            }
        }
    }
    __syncthreads();

    const int t = t0 + tid;
    if (t < T) {
        float acc = 0.0f;
        #pragma unroll
        for (int j = 0; j < NSLOT; ++j)
            acc += P[tid + tb.off[j]];
        out[(size_t)b * T + t] = acc * (1.0f / SENS);
    }
}

extern "C" void kernel_launch(void* const* d_in, const int* in_sizes, int n_in,
                              void* d_out, int out_size, void* d_ws, size_t ws_size,
                              hipStream_t stream) {
    const float* x = (const float*)d_in[0];
    float* out = (float*)d_out;

    const int B = 16;
    const int T = in_sizes[0] / (B * SENS);   // 100000

    // Replicate numpy's delay computation exactly (libm sin, rint half-even).
    int d[SENS];
    const double sv = sin(0.5235987755982988);
    for (int s = 0; s < SENS; ++s)
        d[s] = (int)rint((double)s * sv / 2.0);

    // Fast path requires d[4L..4L+2] == L and d[4L+3] == L+1 for all L.
    bool fast = true;
    for (int L = 0; L < 32; ++L) {
        if (d[4 * L + 0] != L || d[4 * L + 1] != L ||
            d[4 * L + 2] != L || d[4 * L + 3] != L + 1) { fast = false; break; }
    }

    if (fast) {
        dim3 grid((T + FTT - 1) / FTT, B);
        das3_kernel<<<grid, dim3(256), 0, stream>>>(x, out, T);
    } else {
        Tabs tb;
        tb.cm1 = tb.cm2 = tb.cm3 = 0u;
        for (int L = 0; L < 32; ++L) {
            const int d0 = d[4 * L + 0], d1 = d[4 * L + 1];
            const int d2 = d[4 * L + 2], d3 = d[4 * L + 3];
            if (d1 == d0) tb.cm1 |= 1u << L;
            if (d2 == d0) tb.cm2 |= 1u << L;
            if (d3 == d0) tb.cm3 |= 1u << L;
            tb.off[2 * L + 0] = (2 * L + 0) * RSTR + d0;
            tb.off[2 * L + 1] = (2 * L + 1) * RSTR + d3;
        }
        dim3 grid((T + TT - 1) / TT, B);
        das2_kernel<<<grid, dim3(256), 0, stream>>>(x, out, tb, T);
    }
}